// Round 3
// baseline (631.965 us; speedup 1.0000x reference)
//
#include <hip/hip_runtime.h>
#include <math.h>
#include <cstddef>

// Geometry (fixed by the mock config)
#define BB    8
#define SS    4096
#define HH    2048
#define ROWS  (BB*SS)      // 32768 flattened (b,s) rows
#define NC    36           // 24 qkv-conv channels + 8 z + 2 b + 2 a
#define NCP   40           // padded weight row stride (16B-friendly)
#define KSL   128          // per-wave K slice (1024 per k-half / 8 waves)

// native 16B vector for nontemporal builtins (HIP float4 class is rejected)
typedef float vfloat4 __attribute__((ext_vector_type(4)));

// ws layout (floats). Required ws >= (131072 + 2*32768*36)*4 B ~= 10 MB.
#define MIX_OFF 131072     // mix0[ROWS][36], mix1[ROWS][36] after Wt[2048][40]

// ---------------------------------------------------------------------------
// Kernel 0: pack the four projection matrices into transposed Wt[k][c] so the
// GEMM inner loop reads one contiguous 36-float row per k via scalar loads.
__global__ __launch_bounds__(256) void pack_wt(
    const float* __restrict__ w_qkv, const float* __restrict__ w_z,
    const float* __restrict__ w_b,   const float* __restrict__ w_a,
    float* __restrict__ wt) {
  int idx = blockIdx.x * 256 + threadIdx.x;
  if (idx >= HH * NCP) return;
  int k = idx / NCP, c = idx - (idx / NCP) * NCP;
  float v = 0.f;
  if      (c < 24) v = w_qkv[c * HH + k];
  else if (c < 32) v = w_z[(c - 24) * HH + k];
  else if (c < 34) v = w_b[(c - 32) * HH + k];
  else if (c < 36) v = w_a[(c - 34) * HH + k];
  wt[idx] = v;
}

// ---------------------------------------------------------------------------
// Kernel 1 v4: mixed36[r][c] = sum_k x[r][k] * Wt[k][c]
// Register-direct: NO LDS in the main loop. lane = row; each lane streams its
// own row's K-slice via global_load_dwordx4 (64B line fully consumed per
// chunk), FMAs against SGPR weights (wave-uniform wrow -> s_load). lgkmcnt is
// now pure-SMEM (no ds_read mixing -> no forced lgkmcnt(0) drains); vmcnt
// prefetch hides under 1152 cyc of FMA per chunk. K additionally split across
// 2 blocks (khalf) -> 1024 blocks x 8 waves = 8192 waves (grid no longer the
// occupancy cap). Each k-half writes a partial mix; fuse_out sums the two.
__global__ __launch_bounds__(512, 4) void proj36(
    const float* __restrict__ x, const float* __restrict__ wt,
    float* __restrict__ mix) {
  __shared__ float red[8 * 32 * 37];      // 37.9 KB reduction buffer only
  const int tid  = threadIdx.x;
  const int lane = tid & 63;
  const int wv   = __builtin_amdgcn_readfirstlane(tid >> 6);
  const int rblk  = blockIdx.x >> 1;
  const int khalf = blockIdx.x & 1;
  const int r0    = rblk * 64;
  float* mixp = mix + (size_t)khalf * ((size_t)ROWS * NC);

  float acc[NC];
#pragma unroll
  for (int c = 0; c < NC; ++c) acc[c] = 0.f;

  const int kbase = khalf * 1024 + wv * KSL;
  const float* xr = x + (size_t)(r0 + lane) * HH + kbase;

  float4 cur[4];
#pragma unroll
  for (int q = 0; q < 4; ++q) cur[q] = *(const float4*)(xr + q * 4);

#pragma unroll 1
  for (int ch = 0; ch < 8; ++ch) {        // 8 chunks x 16 k
    float4 nxt[4];
    if (ch < 7) {
#pragma unroll
      for (int q = 0; q < 4; ++q)
        nxt[q] = *(const float4*)(xr + (ch + 1) * 16 + q * 4);
    }
    const float* wrow = wt + (size_t)(kbase + ch * 16) * NCP;  // uniform -> s_load
#pragma unroll
    for (int q = 0; q < 4; ++q) {
#pragma unroll
      for (int i = 0; i < 4; ++i) {
        const float xv = (&cur[q].x)[i];
        const float* wk = wrow + (q * 4 + i) * NCP;
#pragma unroll
        for (int c = 0; c < NC; ++c)
          acc[c] = fmaf(wk[c], xv, acc[c]);
      }
    }
    if (ch < 7) {
#pragma unroll
      for (int q = 0; q < 4; ++q) cur[q] = nxt[q];
    }
  }

  // 8-way K reduction in two 32-row passes; red[8 waves][32 rows][37]
  const int rr = lane & 31;
  const int myhalf = lane >> 5;
  for (int half = 0; half < 2; ++half) {
    if (half) __syncthreads();     // previous pass done reading red
    if (myhalf == half) {
#pragma unroll
      for (int c = 0; c < NC; ++c)
        red[(wv * 32 + rr) * 37 + c] = acc[c];
    }
    __syncthreads();
    for (int idx = tid; idx < 32 * NC; idx += 512) {
      int row = idx / NC;
      float s = 0.f;
#pragma unroll
      for (int w = 0; w < 8; ++w) s += red[(w * 32 + row) * 37 + (idx - row * NC)];
      mixp[(size_t)(r0 + half * 32) * NC + idx] = s;   // coalesced 32x36 tile
    }
  }
}

// ---------------------------------------------------------------------------
// Kernel 2: causal depthwise conv + silu + gated-delta elementwise + RMSNorm
// + out-projection. 32 rows per block (1024 blocks = 4/CU); sums the two
// partial mix buffers during LDS staging; non-temporal output stores.
__global__ __launch_bounds__(256) void fuse_out(
    const float* __restrict__ mix,  const float* __restrict__ conv_w,
    const float* __restrict__ dt_bias, const float* __restrict__ A_log,
    const float* __restrict__ norm_w,  const float* __restrict__ w_out,
    float* __restrict__ out) {
  __shared__ float m36[35 * 37];   // rows r0-3 .. r0+31, stride 37
  __shared__ float hb[32 * 8];
  const int tid = threadIdx.x;
  const int r0  = blockIdx.x * 32;
  const float* mix1 = mix + (size_t)ROWS * NC;

  // stage mixed36 tile (+3 halo rows for the conv), summing k-half partials
  const long base = (long)(r0 - 3) * NC;
  for (int idx = tid; idx < 35 * NC; idx += 256) {
    int row = idx / NC, c = idx - row * NC;
    long g = base + idx;
    m36[row * 37 + c] = (g >= 0) ? (mix[g] + mix1[g]) : 0.f;
  }
  __syncthreads();

  if (tid < 64) {                        // 2 threads per row (one per v-head)
    const int row  = tid >> 1, n = tid & 1;
    const int spos = (r0 + row) & (SS - 1);   // position within the batch
    float cv[12];
#pragma unroll
    for (int j = 0; j < 12; ++j) {
      int c = (j >> 2) * 8 + n * 4 + (j & 3); // q:0..7  k:8..15  v:16..23
      float s = 0.f;
#pragma unroll
      for (int k = 0; k < 4; ++k)
        if (spos + k - 3 >= 0) s += m36[(row + k) * 37 + c] * conv_w[c * 4 + k];
      cv[j] = s / (1.f + __expf(-s));         // silu
    }
    float bbv  = m36[(row + 3) * 37 + 32 + n];
    float aav  = m36[(row + 3) * 37 + 34 + n];
    float beta = 1.f / (1.f + __expf(-bbv));
    float spin = aav + dt_bias[n];
    float sp   = (spin > 20.f) ? spin : __logf(1.f + __expf(spin));
    float g    = -__expf(A_log[n]) * sp;
    float core[4], var = 0.f;
#pragma unroll
    for (int d = 0; d < 4; ++d) {
      core[d] = cv[8 + d] + beta * (cv[d] + cv[4 + d]) + g;
      var += core[d] * core[d];
    }
    float rs = rsqrtf(var * 0.25f + 1e-6f);
#pragma unroll
    for (int d = 0; d < 4; ++d) {
      float z = m36[(row + 3) * 37 + 24 + n * 4 + d];
      hb[row * 8 + n * 4 + d] =
          core[d] * rs * norm_w[d] * (z / (1.f + __expf(-z)));
    }
  }
  __syncthreads();

  // out-projection: thread owns cols [4t,4t+3] and [1024+4t, 1024+4t+3]
  const int c0a = tid * 4, c0b = 1024 + tid * 4;
  float4 wr[16];
#pragma unroll
  for (int i = 0; i < 4; ++i) {
    wr[i * 2]     = *(const float4*)(w_out + (size_t)(c0a + i) * 8);
    wr[i * 2 + 1] = *(const float4*)(w_out + (size_t)(c0a + i) * 8 + 4);
    wr[8 + i * 2]     = *(const float4*)(w_out + (size_t)(c0b + i) * 8);
    wr[8 + i * 2 + 1] = *(const float4*)(w_out + (size_t)(c0b + i) * 8 + 4);
  }
  for (int row = 0; row < 32; ++row) {
    float h[8];
#pragma unroll
    for (int v = 0; v < 8; ++v) h[v] = hb[row * 8 + v];   // LDS broadcast
    vfloat4 oa, ob;
#pragma unroll
    for (int i = 0; i < 4; ++i) {
      const float4 wa0 = wr[i * 2], wa1 = wr[i * 2 + 1];
      const float4 wb0 = wr[8 + i * 2], wb1 = wr[8 + i * 2 + 1];
      oa[i] = h[0]*wa0.x + h[1]*wa0.y + h[2]*wa0.z + h[3]*wa0.w
            + h[4]*wa1.x + h[5]*wa1.y + h[6]*wa1.z + h[7]*wa1.w;
      ob[i] = h[0]*wb0.x + h[1]*wb0.y + h[2]*wb0.z + h[3]*wb0.w
            + h[4]*wb1.x + h[5]*wb1.y + h[6]*wb1.z + h[7]*wb1.w;
    }
    float* op = out + (size_t)(r0 + row) * HH;
    __builtin_nontemporal_store(oa, (vfloat4*)(op + c0a));
    __builtin_nontemporal_store(ob, (vfloat4*)(op + c0b));
  }
}

// ---------------------------------------------------------------------------
extern "C" void kernel_launch(void* const* d_in, const int* in_sizes, int n_in,
                              void* d_out, int out_size, void* d_ws, size_t ws_size,
                              hipStream_t stream) {
  (void)in_sizes; (void)n_in; (void)out_size; (void)ws_size;
  const float* x      = (const float*)d_in[0];
  const float* w_qkv  = (const float*)d_in[1];
  const float* w_z    = (const float*)d_in[2];
  const float* w_b    = (const float*)d_in[3];
  const float* w_a    = (const float*)d_in[4];
  const float* w_out  = (const float*)d_in[5];
  const float* conv_w = (const float*)d_in[6];
  const float* dt_b   = (const float*)d_in[7];
  const float* A_log  = (const float*)d_in[8];
  const float* norm_w = (const float*)d_in[9];
  float* out = (float*)d_out;
  float* ws  = (float*)d_ws;
  float* wt  = ws;              // [2048][40]
  float* mix = ws + MIX_OFF;    // mix0[32768][36] then mix1[32768][36]

  pack_wt<<<dim3((HH * NCP + 255) / 256), dim3(256), 0, stream>>>(
      w_qkv, w_z, w_b, w_a, wt);
  proj36<<<dim3(ROWS / 64 * 2), dim3(512), 0, stream>>>(x, wt, mix);
  fuse_out<<<dim3(ROWS / 32), dim3(256), 0, stream>>>(
      mix, conv_w, dt_b, A_log, norm_w, w_out, out);
}

// Round 4
// 521.048 us; speedup vs baseline: 1.2129x; 1.2129x over previous
//
#include <hip/hip_runtime.h>
#include <math.h>
#include <cstddef>

// Geometry (fixed by the mock config)
#define BB    8
#define SS    4096
#define HH    2048
#define ROWS  (BB*SS)      // 32768 flattened (b,s) rows
#define NC    36           // 24 qkv-conv channels + 8 z + 2 b + 2 a
#define NCP   40           // padded weight row stride (16B-friendly)
#define KC    32           // K-chunk per LDS stage (per wave)
#define XST   33           // KC+1: LDS row stride (odd -> conflict-free reads)
#define KSL   256          // per-wave K slice (2048 / 8 waves)
#define TR    61           // output rows per block
#define MR    64           // m-rows per block (TR + 3 conv-halo)
#define NB    ((ROWS + TR - 1) / TR)   // 538 blocks

// native 16B vector for nontemporal builtins (HIP float4 class is rejected)
typedef float vfloat4 __attribute__((ext_vector_type(4)));

// ws: only Wt[2048][40] = 327 KB.

// ---------------------------------------------------------------------------
// Kernel 0: pack the four projection matrices into transposed Wt[k][c] so the
// GEMM inner loop reads one contiguous 36-float row per k via scalar loads.
__global__ __launch_bounds__(256) void pack_wt(
    const float* __restrict__ w_qkv, const float* __restrict__ w_z,
    const float* __restrict__ w_b,   const float* __restrict__ w_a,
    float* __restrict__ wt) {
  int idx = blockIdx.x * 256 + threadIdx.x;
  if (idx >= HH * NCP) return;
  int k = idx / NCP, c = idx - (idx / NCP) * NCP;
  float v = 0.f;
  if      (c < 24) v = w_qkv[c * HH + k];
  else if (c < 32) v = w_z[(c - 24) * HH + k];
  else if (c < 34) v = w_b[(c - 32) * HH + k];
  else if (c < 36) v = w_a[(c - 34) * HH + k];
  wt[idx] = v;
}

// ---------------------------------------------------------------------------
// Fused kernel: projection GEMM (v3-style cooperative LDS staging, 8 waves x
// 256-k slices, SGPR weights) -> mixed36 kept in LDS -> causal conv + silu +
// gated-delta + RMSNorm -> out-projection with nontemporal stores.
// 64 m-rows per block produce 61 output rows (3-row halo recomputed, +5%).
// No global mix intermediate: saves the mix HBM round-trip + a kernel launch.
__global__ __launch_bounds__(512, 4) void fused(
    const float* __restrict__ x,       const float* __restrict__ wt,
    const float* __restrict__ conv_w,  const float* __restrict__ dt_bias,
    const float* __restrict__ A_log,   const float* __restrict__ norm_w,
    const float* __restrict__ w_out,   float* __restrict__ out) {
  __shared__ float sm[8 * MR * XST];   // 67.6 KB staging; aliased as red[]
  __shared__ float m36[MR * 37];       // 9.5 KB mixed36 tile (stride 37)
  __shared__ float hb[TR * 8];         // gated-norm output
  const int tid  = threadIdx.x;
  const int lane = tid & 63;
  const int wv   = __builtin_amdgcn_readfirstlane(tid >> 6);
  const int r0   = blockIdx.x * TR;    // first output row
  const int rm0  = r0 - 3;             // first m-row (conv halo)

  // ---- Phase 1: proj36 into LDS ------------------------------------------
  float* xs = sm + wv * MR * XST;      // this wave's private staging region
  float acc[NC];
#pragma unroll
  for (int c = 0; c < NC; ++c) acc[c] = 0.f;

  const int kbase = wv * KSL;
  const int srow = lane >> 3;          // 8 rows per staging pass
  const int scol = (lane & 7) * 4;     // 8 lanes x float4 = 128B/row segment

  // 8 clamped row base pointers (halo rows outside [0,ROWS) are clamped;
  // their values are finite and provably never used by the spos guard).
  const float* rp[8];
#pragma unroll
  for (int p = 0; p < 8; ++p) {
    int rg = rm0 + p * 8 + srow;
    rg = rg < 0 ? 0 : (rg > ROWS - 1 ? ROWS - 1 : rg);
    rp[p] = x + (size_t)rg * HH + kbase + scol;
  }

  float4 buf[8];
#pragma unroll
  for (int p = 0; p < 8; ++p) buf[p] = *(const float4*)(rp[p]);

  for (int ch = 0; ch < 8; ++ch) {     // 8 chunks x 32 k
    // LDS write of current chunk (odd stride -> conflict-free reads)
#pragma unroll
    for (int p = 0; p < 8; ++p) {
      float* dst = xs + (p * 8 + srow) * XST + scol;
      dst[0] = buf[p].x; dst[1] = buf[p].y; dst[2] = buf[p].z; dst[3] = buf[p].w;
    }
    // prefetch next chunk (overlaps compute below)
    if (ch < 7) {
#pragma unroll
      for (int p = 0; p < 8; ++p)
        buf[p] = *(const float4*)(rp[p] + (ch + 1) * KC);
    }
    const float* wrow = wt + (size_t)(kbase + ch * KC) * NCP; // uniform -> s_load
    const float* xr = xs + lane * XST;
#pragma unroll 2
    for (int k = 0; k < KC; ++k) {
      float xv = xr[k];
#pragma unroll
      for (int c = 0; c < NC; ++c)
        acc[c] = fmaf(wrow[k * NCP + c], xv, acc[c]);
    }
    // no barrier: xs region is wave-private
  }
  __syncthreads();                     // all waves done with staging regions

  // ---- Reduce 8 wave K-partials -> m36, two 32-row passes ----------------
  const int rr = lane & 31;
  const int hsel = lane >> 5;
  for (int half = 0; half < 2; ++half) {
    if (half) __syncthreads();         // previous pass done reading sm
    if (hsel == half) {
#pragma unroll
      for (int c = 0; c < NC; ++c)
        sm[(wv * 32 + rr) * 37 + c] = acc[c];
    }
    __syncthreads();
    for (int idx = tid; idx < 32 * NC; idx += 512) {
      int row = idx / NC, c = idx - row * NC;
      float s = 0.f;
#pragma unroll
      for (int w = 0; w < 8; ++w) s += sm[(w * 32 + row) * 37 + c];
      m36[(half * 32 + row) * 37 + c] = s;
    }
  }
  __syncthreads();

  // ---- Phase 2: conv + silu + gated-delta + RMSNorm-gate -> hb -----------
  if (tid < 2 * TR) {                  // 2 threads per output row (v-heads)
    const int j = tid >> 1, n = tid & 1;     // output row r0+j, m-row j+3
    const int spos = (r0 + j) & (SS - 1);    // position within the batch
    float cv[12];
#pragma unroll
    for (int jj = 0; jj < 12; ++jj) {
      int c = (jj >> 2) * 8 + n * 4 + (jj & 3); // q:0..7 k:8..15 v:16..23
      float s = 0.f;
#pragma unroll
      for (int k = 0; k < 4; ++k)
        if (spos + k - 3 >= 0) s += m36[(j + k) * 37 + c] * conv_w[c * 4 + k];
      cv[jj] = s / (1.f + __expf(-s));        // silu
    }
    float bbv  = m36[(j + 3) * 37 + 32 + n];
    float aav  = m36[(j + 3) * 37 + 34 + n];
    float beta = 1.f / (1.f + __expf(-bbv));
    float spin = aav + dt_bias[n];
    float sp   = (spin > 20.f) ? spin : __logf(1.f + __expf(spin));
    float g    = -__expf(A_log[n]) * sp;
    float core[4], var = 0.f;
#pragma unroll
    for (int d = 0; d < 4; ++d) {
      core[d] = cv[8 + d] + beta * (cv[d] + cv[4 + d]) + g;
      var += core[d] * core[d];
    }
    float rs = rsqrtf(var * 0.25f + 1e-6f);
#pragma unroll
    for (int d = 0; d < 4; ++d) {
      float z = m36[(j + 3) * 37 + 24 + n * 4 + d];
      hb[j * 8 + n * 4 + d] =
          core[d] * rs * norm_w[d] * (z / (1.f + __expf(-z)));
    }
  }
  __syncthreads();

  // ---- Phase 3: out-projection; thread owns cols [4t, 4t+3] --------------
  const int c0 = tid * 4;              // 512 threads x 4 = 2048 cols
  float4 w0[4], w1[4];
#pragma unroll
  for (int i = 0; i < 4; ++i) {
    w0[i] = *(const float4*)(w_out + (size_t)(c0 + i) * 8);
    w1[i] = *(const float4*)(w_out + (size_t)(c0 + i) * 8 + 4);
  }
  const int jmax = (ROWS - r0 < TR) ? (ROWS - r0) : TR;
  for (int j = 0; j < jmax; ++j) {
    float h[8];
#pragma unroll
    for (int v = 0; v < 8; ++v) h[v] = hb[j * 8 + v];   // LDS broadcast
    vfloat4 o;
#pragma unroll
    for (int i = 0; i < 4; ++i)
      o[i] = h[0]*w0[i].x + h[1]*w0[i].y + h[2]*w0[i].z + h[3]*w0[i].w
           + h[4]*w1[i].x + h[5]*w1[i].y + h[6]*w1[i].z + h[7]*w1[i].w;
    __builtin_nontemporal_store(o, (vfloat4*)(out + (size_t)(r0 + j) * HH + c0));
  }
}

// ---------------------------------------------------------------------------
extern "C" void kernel_launch(void* const* d_in, const int* in_sizes, int n_in,
                              void* d_out, int out_size, void* d_ws, size_t ws_size,
                              hipStream_t stream) {
  (void)in_sizes; (void)n_in; (void)out_size; (void)ws_size;
  const float* x      = (const float*)d_in[0];
  const float* w_qkv  = (const float*)d_in[1];
  const float* w_z    = (const float*)d_in[2];
  const float* w_b    = (const float*)d_in[3];
  const float* w_a    = (const float*)d_in[4];
  const float* w_out  = (const float*)d_in[5];
  const float* conv_w = (const float*)d_in[6];
  const float* dt_b   = (const float*)d_in[7];
  const float* A_log  = (const float*)d_in[8];
  const float* norm_w = (const float*)d_in[9];
  float* out = (float*)d_out;
  float* wt  = (float*)d_ws;    // [2048][40]

  pack_wt<<<dim3((HH * NCP + 255) / 256), dim3(256), 0, stream>>>(
      w_qkv, w_z, w_b, w_a, wt);
  fused<<<dim3(NB), dim3(512), 0, stream>>>(
      x, wt, conv_w, dt_b, A_log, norm_w, w_out, out);
}

// Round 5
// 489.387 us; speedup vs baseline: 1.2913x; 1.0647x over previous
//
#include <hip/hip_runtime.h>
#include <math.h>
#include <cstddef>

// Geometry (fixed by the mock config)
#define BB    8
#define SS    4096
#define HH    2048
#define ROWS  (BB*SS)      // 32768 flattened (b,s) rows
#define NC    36           // 24 qkv-conv channels + 8 z + 2 b + 2 a
#define KC    16           // K-chunk per LDS stage (per wave)
#define XST   17           // KC+1: x LDS row stride (conflict-free b32 reads)
#define KSL   256          // per-wave K slice (2048 / 8 waves)
#define NCH   16           // chunks per wave (KSL / KC)

// LDS plan (floats): x slabs 8*64*17 = 8704, w slabs 8*16*36 = 4608
#define XSLAB (64 * XST)       // 1088 per wave
#define WOFF  (8 * XSLAB)      // 8704
#define WSLAB (KC * NC)        // 576 per wave
#define LDSZ  (WOFF + 8 * WSLAB)   // 13312 floats = 53.2 KB

// native 16B vector for nontemporal builtins (HIP float4 class is rejected)
typedef float vfloat4 __attribute__((ext_vector_type(4)));

// ws layout (floats). Required ws >= (73728 + 32768*36)*4 B ~= 5 MB.
#define MIX_OFF (HH * NC)      // mixed36[ROWS][36] after Wt[2048][36]

// ---------------------------------------------------------------------------
// Kernel 0: pack the four projection matrices into transposed, COMPACT
// Wt[k][36] (144 B rows, 16B-aligned) for ds_read_b128-friendly LDS staging.
__global__ __launch_bounds__(256) void pack_wt(
    const float* __restrict__ w_qkv, const float* __restrict__ w_z,
    const float* __restrict__ w_b,   const float* __restrict__ w_a,
    float* __restrict__ wt) {
  int idx = blockIdx.x * 256 + threadIdx.x;
  if (idx >= HH * NC) return;
  int k = idx / NC, c = idx - (idx / NC) * NC;
  float v;
  if      (c < 24) v = w_qkv[c * HH + k];
  else if (c < 32) v = w_z[(c - 24) * HH + k];
  else if (c < 34) v = w_b[(c - 32) * HH + k];
  else             v = w_a[(c - 34) * HH + k];
  wt[idx] = v;
}

// ---------------------------------------------------------------------------
// Kernel 1 v5: mixed36[r][c] = sum_k x[r][k] * Wt[k][c]
// 8 waves x 256-k slices over the same 64 rows (lane = row). Weights now go
// global -> LDS (wave-private slab) and are read with wave-uniform
// ds_read_b128 (hardware broadcast, conflict-free) instead of s_load: VGPR-
// destination loads pipeline deeply on lgkmcnt, removing the SGPR-depth-
// limited SMEM stall (SGPR file only held ~2 k-iters of weights in flight).
// x is staged per-wave as before (coalesced float4, odd stride). Both slabs
// are wave-private -> ZERO barriers in the main loop.
__global__ __launch_bounds__(512, 4) void proj36(
    const float* __restrict__ x, const float* __restrict__ wt,
    float* __restrict__ mix) {
  __shared__ float lds[LDSZ];          // 53.2 KB; aliased as red[] at the end
  const int tid  = threadIdx.x;
  const int lane = tid & 63;
  const int wv   = __builtin_amdgcn_readfirstlane(tid >> 6);
  const int r0   = blockIdx.x * 64;

  float* xs = lds + wv * XSLAB;                // wave-private x slab
  float* wl = lds + WOFF + wv * WSLAB;         // wave-private weight slab

  float acc[NC];
#pragma unroll
  for (int c = 0; c < NC; ++c) acc[c] = 0.f;

  const int kbase = wv * KSL;
  const int srow = lane >> 2;                  // 16 rows per staging pass
  const int scol = (lane & 3) * 4;             // 4 lanes x float4 = 64B/row

  const float* xg = x + (size_t)(r0 + srow) * HH + kbase + scol;
  const float* wg = wt + (size_t)kbase * NC + lane;   // + i*64 per element

  // initial prefetch (chunk 0)
  float4 xbuf[4];
  float  wbuf[9];
#pragma unroll
  for (int p = 0; p < 4; ++p)
    xbuf[p] = *(const float4*)(xg + (size_t)(p * 16) * HH);
#pragma unroll
  for (int i = 0; i < 9; ++i) wbuf[i] = wg[i * 64];

#pragma unroll 1
  for (int ch = 0; ch < NCH; ++ch) {
    // write staged regs -> wave-private LDS
#pragma unroll
    for (int p = 0; p < 4; ++p) {
      float* dst = xs + (p * 16 + srow) * XST + scol;
      dst[0] = xbuf[p].x; dst[1] = xbuf[p].y;
      dst[2] = xbuf[p].z; dst[3] = xbuf[p].w;
    }
#pragma unroll
    for (int i = 0; i < 9; ++i) wl[i * 64 + lane] = wbuf[i];

    // prefetch next chunk into registers (overlaps compute)
    if (ch < NCH - 1) {
      const float* xg2 = xg + (ch + 1) * KC;
      const float* wg2 = wg + (size_t)(ch + 1) * KC * NC;
#pragma unroll
      for (int p = 0; p < 4; ++p)
        xbuf[p] = *(const float4*)(xg2 + (size_t)(p * 16) * HH);
#pragma unroll
      for (int i = 0; i < 9; ++i) wbuf[i] = wg2[i * 64];
    }

    // compute: per k, 1 b32 x-read + 9 uniform b128 weight-reads + 36 FMA
    const float* xr = xs + lane * XST;
#pragma unroll
    for (int k = 0; k < KC; ++k) {
      const float xv = xr[k];
      const float* wk = wl + k * NC;
#pragma unroll
      for (int c4 = 0; c4 < 9; ++c4) {
        const float4 w4 = *(const float4*)(wk + c4 * 4);
        acc[c4 * 4 + 0] = fmaf(w4.x, xv, acc[c4 * 4 + 0]);
        acc[c4 * 4 + 1] = fmaf(w4.y, xv, acc[c4 * 4 + 1]);
        acc[c4 * 4 + 2] = fmaf(w4.z, xv, acc[c4 * 4 + 2]);
        acc[c4 * 4 + 3] = fmaf(w4.w, xv, acc[c4 * 4 + 3]);
      }
    }
    // no barrier: both slabs are wave-private; in-wave lgkmcnt ordering
  }

  __syncthreads();                 // all waves done with their slabs
  // 8-way K reduction in two 32-row passes; red[8 waves][32 rows][37]
  const int rr = lane & 31;
  const int hsel = lane >> 5;
  for (int half = 0; half < 2; ++half) {
    if (half) __syncthreads();     // previous pass done reading red
    if (hsel == half) {
#pragma unroll
      for (int c = 0; c < NC; ++c)
        lds[(wv * 32 + rr) * 37 + c] = acc[c];
    }
    __syncthreads();
    for (int idx = tid; idx < 32 * NC; idx += 512) {
      int row = idx / NC;
      float s = 0.f;
#pragma unroll
      for (int w = 0; w < 8; ++w) s += lds[(w * 32 + row) * 37 + (idx - row * NC)];
      mix[(size_t)(r0 + half * 32) * NC + idx] = s;   // coalesced 32x36 tile
    }
  }
}

// ---------------------------------------------------------------------------
// Kernel 2: causal depthwise conv + silu + gated-delta elementwise + RMSNorm
// + out-projection. 32 rows per block (1024 blocks = 4/CU); non-temporal
// stores for the 256 MB output stream.
__global__ __launch_bounds__(256) void fuse_out(
    const float* __restrict__ mix,  const float* __restrict__ conv_w,
    const float* __restrict__ dt_bias, const float* __restrict__ A_log,
    const float* __restrict__ norm_w,  const float* __restrict__ w_out,
    float* __restrict__ out) {
  __shared__ float m36[35 * 37];   // rows r0-3 .. r0+31, stride 37
  __shared__ float hb[32 * 8];
  const int tid = threadIdx.x;
  const int r0  = blockIdx.x * 32;

  // stage mixed36 tile (+3 halo rows for the conv)
  const long base = (long)(r0 - 3) * NC;
  for (int idx = tid; idx < 35 * NC; idx += 256) {
    int row = idx / NC, c = idx - row * NC;
    long g = base + idx;
    m36[row * 37 + c] = (g >= 0) ? mix[g] : 0.f;
  }
  __syncthreads();

  if (tid < 64) {                        // 2 threads per row (one per v-head)
    const int row  = tid >> 1, n = tid & 1;
    const int spos = (r0 + row) & (SS - 1);   // position within the batch
    float cv[12];
#pragma unroll
    for (int j = 0; j < 12; ++j) {
      int c = (j >> 2) * 8 + n * 4 + (j & 3); // q:0..7  k:8..15  v:16..23
      float s = 0.f;
#pragma unroll
      for (int k = 0; k < 4; ++k)
        if (spos + k - 3 >= 0) s += m36[(row + k) * 37 + c] * conv_w[c * 4 + k];
      cv[j] = s / (1.f + __expf(-s));         // silu
    }
    float bbv  = m36[(row + 3) * 37 + 32 + n];
    float aav  = m36[(row + 3) * 37 + 34 + n];
    float beta = 1.f / (1.f + __expf(-bbv));
    float spin = aav + dt_bias[n];
    float sp   = (spin > 20.f) ? spin : __logf(1.f + __expf(spin));
    float g    = -__expf(A_log[n]) * sp;
    float core[4], var = 0.f;
#pragma unroll
    for (int d = 0; d < 4; ++d) {
      core[d] = cv[8 + d] + beta * (cv[d] + cv[4 + d]) + g;
      var += core[d] * core[d];
    }
    float rs = rsqrtf(var * 0.25f + 1e-6f);
#pragma unroll
    for (int d = 0; d < 4; ++d) {
      float z = m36[(row + 3) * 37 + 24 + n * 4 + d];
      hb[row * 8 + n * 4 + d] =
          core[d] * rs * norm_w[d] * (z / (1.f + __expf(-z)));
    }
  }
  __syncthreads();

  // out-projection: thread owns cols [4t,4t+3] and [1024+4t, 1024+4t+3]
  const int c0a = tid * 4, c0b = 1024 + tid * 4;
  float4 wr[16];
#pragma unroll
  for (int i = 0; i < 4; ++i) {
    wr[i * 2]     = *(const float4*)(w_out + (size_t)(c0a + i) * 8);
    wr[i * 2 + 1] = *(const float4*)(w_out + (size_t)(c0a + i) * 8 + 4);
    wr[8 + i * 2]     = *(const float4*)(w_out + (size_t)(c0b + i) * 8);
    wr[8 + i * 2 + 1] = *(const float4*)(w_out + (size_t)(c0b + i) * 8 + 4);
  }
  for (int row = 0; row < 32; ++row) {
    float h[8];
#pragma unroll
    for (int v = 0; v < 8; ++v) h[v] = hb[row * 8 + v];   // LDS broadcast
    vfloat4 oa, ob;
#pragma unroll
    for (int i = 0; i < 4; ++i) {
      const float4 wa0 = wr[i * 2], wa1 = wr[i * 2 + 1];
      const float4 wb0 = wr[8 + i * 2], wb1 = wr[8 + i * 2 + 1];
      oa[i] = h[0]*wa0.x + h[1]*wa0.y + h[2]*wa0.z + h[3]*wa0.w
            + h[4]*wa1.x + h[5]*wa1.y + h[6]*wa1.z + h[7]*wa1.w;
      ob[i] = h[0]*wb0.x + h[1]*wb0.y + h[2]*wb0.z + h[3]*wb0.w
            + h[4]*wb1.x + h[5]*wb1.y + h[6]*wb1.z + h[7]*wb1.w;
    }
    float* op = out + (size_t)(r0 + row) * HH;
    __builtin_nontemporal_store(oa, (vfloat4*)(op + c0a));
    __builtin_nontemporal_store(ob, (vfloat4*)(op + c0b));
  }
}

// ---------------------------------------------------------------------------
extern "C" void kernel_launch(void* const* d_in, const int* in_sizes, int n_in,
                              void* d_out, int out_size, void* d_ws, size_t ws_size,
                              hipStream_t stream) {
  (void)in_sizes; (void)n_in; (void)out_size; (void)ws_size;
  const float* x      = (const float*)d_in[0];
  const float* w_qkv  = (const float*)d_in[1];
  const float* w_z    = (const float*)d_in[2];
  const float* w_b    = (const float*)d_in[3];
  const float* w_a    = (const float*)d_in[4];
  const float* w_out  = (const float*)d_in[5];
  const float* conv_w = (const float*)d_in[6];
  const float* dt_b   = (const float*)d_in[7];
  const float* A_log  = (const float*)d_in[8];
  const float* norm_w = (const float*)d_in[9];
  float* out = (float*)d_out;
  float* ws  = (float*)d_ws;
  float* wt  = ws;              // [2048][36] compact
  float* mix = ws + MIX_OFF;    // [32768][36]

  pack_wt<<<dim3((HH * NC + 255) / 256), dim3(256), 0, stream>>>(
      w_qkv, w_z, w_b, w_a, wt);
  proj36<<<dim3(ROWS / 64), dim3(512), 0, stream>>>(x, wt, mix);
  fuse_out<<<dim3(ROWS / 32), dim3(256), 0, stream>>>(
      mix, conv_w, dt_b, A_log, norm_w, w_out, out);
}